// Round 2
// baseline (476.141 us; speedup 1.0000x reference)
//
#include <hip/hip_runtime.h>

// Swin shifted-window attention, MI355X gfx950.
// f16 MFMA (16x16x32), fp32 accumulate + fp32 softmax.
// Pipeline: k_pre (gather+cvt x->f16) -> k_qkv (GEMM) -> k_attn -> k_out (GEMM+scatter).
// d_out doubles as q|k f16 buffer until k_out overwrites it with fp32 output.
// ws: [0,64MiB) xg (f16 gathered x), later reused as ao; [64,128MiB) vt (V transposed).

using f16   = _Float16;
using f16x8 = __attribute__((ext_vector_type(8))) _Float16;
using f16x4 = __attribute__((ext_vector_type(4))) _Float16;
using f32x4 = __attribute__((ext_vector_type(4))) float;

#define MFMA16(a, b, c) __builtin_amdgcn_mfma_f32_16x16x32_f16((a), (b), (c), 0, 0, 0)

static constexpr int QK_HALF = 65536 * 512;  // element offset of k-region inside d_out overlay

typedef const __attribute__((address_space(1))) unsigned int* gp_t;
typedef __attribute__((address_space(3))) unsigned int* sp_t;
__device__ __forceinline__ void gl_lds16(const f16* g, f16* s) {
  // async global->LDS, 16B/lane; LDS dest = wave-uniform base + lane*16 (linear)
  __builtin_amdgcn_global_load_lds((gp_t)g, (sp_t)s, 16, 0, 0);
}

// token t (window-partition order, rolled frame) -> element offset of its patch row.
__device__ __forceinline__ int tok2patch(int t) {
  int b = t >> 12, rem = t & 4095;
  int widx = rem >> 6, s = rem & 63;
  int pr = (((widx >> 3) << 3) + (s >> 3) + 4) & 63;
  int pc = (((widx & 7) << 3) + (s & 7) + 4) & 63;
  return ((b << 12) | (pr << 6) | pc) << 9;  // *512 channels
}

__device__ __forceinline__ f16x8 cvt8(float4 a, float4 b) {
  f16x8 h = { (f16)a.x, (f16)a.y, (f16)a.z, (f16)a.w,
              (f16)b.x, (f16)b.y, (f16)b.z, (f16)b.w };
  return h;
}

// ---------------------------------------------------------------------------
// Kernel 0: gather (roll -4 + window partition) + fp32->f16.  16 tokens/block.
// ---------------------------------------------------------------------------
__global__ __launch_bounds__(256) void k_pre(const float* __restrict__ x,
                                             f16* __restrict__ xg) {
  const int t = blockIdx.x * 16 + (threadIdx.x >> 4);
  const int i = threadIdx.x & 15;
  const float4* src = (const float4*)(x + tok2patch(t));
  f16x4* dst = (f16x4*)(xg + t * 512);
#pragma unroll
  for (int j = 0; j < 8; ++j) {
    float4 v = src[i + j * 16];
    f16x4 h = { (f16)v.x, (f16)v.y, (f16)v.z, (f16)v.w };
    dst[i + j * 16] = h;
  }
}

// ---------------------------------------------------------------------------
// GEMM tiles: BM=128, BN=128, BK=64, 4 waves (2x2), 64x64 per wave.
// LDS layout [128 rows][8 chunks of 16B], slot (r,c) holds K-chunk c^(r&7):
//   A: linear gload_lds dest + inverse-swizzled per-lane GLOBAL source (m201/rule 21)
//   B: reg-staged (fp32 w -> cvt f16) with swizzled ds_write
//   fragment reads XOR the chunk with (row&7) -> conflict-free (8-cyc floor).
// ---------------------------------------------------------------------------

// Kernel 1: QKV projection.  qkv[t,n] = xg[t,:] . wq[n,:] + bq[n]
__global__ __launch_bounds__(256) void k_qkv(const f16* __restrict__ xg,
                                             const float* __restrict__ wq,
                                             const float* __restrict__ bq,
                                             f16* __restrict__ qk,
                                             f16* __restrict__ vt) {
  __shared__ f16 As[128 * 64];
  __shared__ f16 Bs[128 * 64];
  const int bid = blockIdx.x;                       // 6144 blocks
  const int wgid = (bid & 7) * 768 + (bid >> 3);    // bijective XCD chunking
  const int bm = wgid / 12, bn = wgid - bm * 12;
  const int tid = threadIdx.x;
  const int lane = tid & 63, wave = tid >> 6;
  const int jlo = lane & 15, g = lane >> 4;
  const int wrow = (wave >> 1) * 64, wcol = (wave & 1) * 64;

  // A staging: wave covers LDS rows [wave*32, wave*32+32), 4 x 1KB instructions
  const int ar = wave * 32 + (lane >> 3);
  const int aq = (lane & 7) ^ ((lane >> 3) & 7);    // pre-swizzled global chunk
  const f16* asrc = xg + (bm * 128 + ar) * 512 + aq * 8;
  f16* aldsb = As + wave * 2048;                    // wave-uniform base

  // B staging: thread covers row nl, fp32 cols [h2*32, h2*32+32)
  const int nl = tid & 127, h2 = tid >> 7;
  const float* bsrc = wq + (bn * 128 + nl) * 512 + h2 * 32;

  float4 rb[8];
#define LOADB(K)                                                  \
  do {                                                            \
    _Pragma("unroll") for (int j = 0; j < 8; ++j)                 \
        rb[j] = *(const float4*)(bsrc + (K) + j * 4);             \
  } while (0)

  f32x4 acc[4][4] = {};
  LOADB(0);
  for (int k0 = 0; k0 < 512; k0 += 64) {
#pragma unroll
    for (int i = 0; i < 4; ++i)
      gl_lds16(asrc + k0 + i * 8 * 512, aldsb + i * 512);
#pragma unroll
    for (int q = 0; q < 4; ++q)
      *(f16x8*)(Bs + nl * 64 + (((h2 * 4 + q) ^ (nl & 7)) * 8)) = cvt8(rb[2 * q], rb[2 * q + 1]);
    __syncthreads();  // drains gload_lds (vmcnt0) + ds_writes
    if (k0 < 448) LOADB(k0 + 64);  // prefetch next B under MFMAs
#pragma unroll
    for (int ks = 0; ks < 2; ++ks) {
      f16x8 af[4], bf[4];
#pragma unroll
      for (int mt = 0; mt < 4; ++mt) {
        int m = wrow + mt * 16 + jlo;
        af[mt] = *(const f16x8*)(As + m * 64 + (((ks * 4 + g) ^ (m & 7)) * 8));
      }
#pragma unroll
      for (int nt = 0; nt < 4; ++nt) {
        int n = wcol + nt * 16 + jlo;
        bf[nt] = *(const f16x8*)(Bs + n * 64 + (((ks * 4 + g) ^ (n & 7)) * 8));
      }
#pragma unroll
      for (int mt = 0; mt < 4; ++mt)
#pragma unroll
        for (int nt = 0; nt < 4; ++nt)
          acc[mt][nt] = MFMA16(af[mt], bf[nt], acc[mt][nt]);
    }
    __syncthreads();
  }
#undef LOADB

  // epilogue: D layout col = lane&15, row = (lane>>4)*4 + reg
#pragma unroll
  for (int nt = 0; nt < 4; ++nt) {
    const int colg = bn * 128 + wcol + nt * 16 + jlo;  // 0..1535
    const float bias = bq[colg];
    if (colg < 1024) {  // q or k -> row-major f16 into d_out overlay
      const int base = (colg < 512) ? colg : (colg - 512 + QK_HALF);
#pragma unroll
      for (int mt = 0; mt < 4; ++mt) {
        const int t0 = bm * 128 + wrow + mt * 16 + g * 4;
#pragma unroll
        for (int r = 0; r < 4; ++r)
          qk[base + (t0 + r) * 512] = (f16)(acc[mt][nt][r] + bias);
      }
    } else {  // v -> transposed per (window, head): vt[w][h][d][s]
      const int n = colg - 1024, h = n >> 5, d = n & 31;
#pragma unroll
      for (int mt = 0; mt < 4; ++mt) {
        const int t0 = bm * 128 + wrow + mt * 16 + g * 4;
        const int w = t0 >> 6, s0 = t0 & 63;
        f16x4 pk = { (f16)(acc[mt][nt][0] + bias), (f16)(acc[mt][nt][1] + bias),
                     (f16)(acc[mt][nt][2] + bias), (f16)(acc[mt][nt][3] + bias) };
        *(f16x4*)(vt + ((w * 16 + h) * 32 + d) * 64 + s0) = pk;
      }
    }
  }
}

// ---------------------------------------------------------------------------
// Kernel 2: per-window attention (unchanged from R0, verified).
// ---------------------------------------------------------------------------
__global__ __launch_bounds__(256) void k_attn(const f16* __restrict__ qk,
                                              const f16* __restrict__ vt,
                                              f16* __restrict__ ao) {
  __shared__ f16 P[4][64 * 72];
  const int w = blockIdx.x;
  const int widx = w & 63;
  const bool er = (widx >> 3) == 7;
  const bool ec = (widx & 7) == 7;
  const int tid = threadIdx.x;
  const int lane = tid & 63, wave = tid >> 6;
  const int jlo = lane & 15, g = lane >> 4;
  const int tb = w * 64;
  f16* Pw = P[wave];
  const float scale = 0.17677669529663687f;

#pragma unroll 1
  for (int hh = 0; hh < 4; ++hh) {
    const int h = wave * 4 + hh;
    f16x8 qa[4], kb[4];
#pragma unroll
    for (int mt = 0; mt < 4; ++mt)
      qa[mt] = *(const f16x8*)(qk + (tb + mt * 16 + jlo) * 512 + h * 32 + g * 8);
#pragma unroll
    for (int nt = 0; nt < 4; ++nt)
      kb[nt] = *(const f16x8*)(qk + QK_HALF + (tb + nt * 16 + jlo) * 512 + h * 32 + g * 8);
    f32x4 sc[4][4] = {};
#pragma unroll
    for (int mt = 0; mt < 4; ++mt)
#pragma unroll
      for (int nt = 0; nt < 4; ++nt)
        sc[mt][nt] = MFMA16(qa[mt], kb[nt], sc[mt][nt]);

    int gj[4];
#pragma unroll
    for (int nt = 0; nt < 4; ++nt) {
      int j = nt * 16 + jlo;
      gj[nt] = ((er && ((j >> 3) >= 4)) ? 2 : 0) | ((ec && ((j & 7) >= 4)) ? 1 : 0);
    }
    float rinv[4][4];
#pragma unroll
    for (int mt = 0; mt < 4; ++mt) {
#pragma unroll
      for (int r = 0; r < 4; ++r) {
        const int i = mt * 16 + g * 4 + r;
        const int gi = ((er && ((i >> 3) >= 4)) ? 2 : 0) | ((ec && ((i & 7) >= 4)) ? 1 : 0);
        float v0 = (gi == gj[0]) ? sc[mt][0][r] * scale : -1e9f;
        float v1 = (gi == gj[1]) ? sc[mt][1][r] * scale : -1e9f;
        float v2 = (gi == gj[2]) ? sc[mt][2][r] * scale : -1e9f;
        float v3 = (gi == gj[3]) ? sc[mt][3][r] * scale : -1e9f;
        float m = fmaxf(fmaxf(v0, v1), fmaxf(v2, v3));
        m = fmaxf(m, __shfl_xor(m, 1));
        m = fmaxf(m, __shfl_xor(m, 2));
        m = fmaxf(m, __shfl_xor(m, 4));
        m = fmaxf(m, __shfl_xor(m, 8));
        float p0 = __expf(v0 - m), p1 = __expf(v1 - m);
        float p2 = __expf(v2 - m), p3 = __expf(v3 - m);
        float s = p0 + p1 + p2 + p3;
        s += __shfl_xor(s, 1);
        s += __shfl_xor(s, 2);
        s += __shfl_xor(s, 4);
        s += __shfl_xor(s, 8);
        rinv[mt][r] = 1.0f / s;
        sc[mt][0][r] = p0; sc[mt][1][r] = p1; sc[mt][2][r] = p2; sc[mt][3][r] = p3;
      }
    }
#pragma unroll
    for (int mt = 0; mt < 4; ++mt)
#pragma unroll
      for (int nt = 0; nt < 4; ++nt)
#pragma unroll
        for (int r = 0; r < 4; ++r)
          Pw[(mt * 16 + g * 4 + r) * 72 + nt * 16 + jlo] = (f16)sc[mt][nt][r];
    asm volatile("s_waitcnt lgkmcnt(0)" ::: "memory");

    f32x4 o[4][2] = {};
#pragma unroll
    for (int ks = 0; ks < 2; ++ks) {
      f16x8 pa[4], vb[2];
#pragma unroll
      for (int mt = 0; mt < 4; ++mt)
        pa[mt] = *(const f16x8*)((const char*)Pw + (mt * 16 + jlo) * 144 + ks * 64 + g * 16);
#pragma unroll
      for (int nt = 0; nt < 2; ++nt)
        vb[nt] = *(const f16x8*)(vt + ((w * 16 + h) * 32 + nt * 16 + jlo) * 64 + ks * 32 + g * 8);
#pragma unroll
      for (int mt = 0; mt < 4; ++mt)
#pragma unroll
        for (int nt = 0; nt < 2; ++nt)
          o[mt][nt] = MFMA16(pa[mt], vb[nt], o[mt][nt]);
    }
#pragma unroll
    for (int mt = 0; mt < 4; ++mt)
#pragma unroll
      for (int nt = 0; nt < 2; ++nt)
#pragma unroll
        for (int r = 0; r < 4; ++r)
          ao[(tb + mt * 16 + g * 4 + r) * 512 + h * 32 + nt * 16 + jlo] =
              (f16)(o[mt][nt][r] * rinv[mt][r]);
  }
}

// ---------------------------------------------------------------------------
// Kernel 3: output projection + window-merge + roll(+4) scatter (fp32 out).
// ---------------------------------------------------------------------------
__global__ __launch_bounds__(256) void k_out(const f16* __restrict__ ao,
                                             const float* __restrict__ wo,
                                             const float* __restrict__ bo,
                                             float* __restrict__ out) {
  __shared__ f16 As[128 * 64];
  __shared__ f16 Bs[128 * 64];
  __shared__ int rowoff[128];
  const int bid = blockIdx.x;                     // 2048 blocks
  const int wgid = (bid & 7) * 256 + (bid >> 3);  // XCD chunking
  const int bm = wgid >> 2, bn = wgid & 3;
  const int tid = threadIdx.x;
  if (tid < 128) rowoff[tid] = tok2patch(bm * 128 + tid);
  __syncthreads();
  const int lane = tid & 63, wave = tid >> 6;
  const int jlo = lane & 15, g = lane >> 4;
  const int wrow = (wave >> 1) * 64, wcol = (wave & 1) * 64;

  const int ar = wave * 32 + (lane >> 3);
  const int aq = (lane & 7) ^ ((lane >> 3) & 7);
  const f16* asrc = ao + (bm * 128 + ar) * 512 + aq * 8;
  f16* aldsb = As + wave * 2048;

  const int nl = tid & 127, h2 = tid >> 7;
  const float* bsrc = wo + (bn * 128 + nl) * 512 + h2 * 32;

  float4 rb[8];
#define LOADB(K)                                                  \
  do {                                                            \
    _Pragma("unroll") for (int j = 0; j < 8; ++j)                 \
        rb[j] = *(const float4*)(bsrc + (K) + j * 4);             \
  } while (0)

  f32x4 acc[4][4] = {};
  LOADB(0);
  for (int k0 = 0; k0 < 512; k0 += 64) {
#pragma unroll
    for (int i = 0; i < 4; ++i)
      gl_lds16(asrc + k0 + i * 8 * 512, aldsb + i * 512);
#pragma unroll
    for (int q = 0; q < 4; ++q)
      *(f16x8*)(Bs + nl * 64 + (((h2 * 4 + q) ^ (nl & 7)) * 8)) = cvt8(rb[2 * q], rb[2 * q + 1]);
    __syncthreads();
    if (k0 < 448) LOADB(k0 + 64);
#pragma unroll
    for (int ks = 0; ks < 2; ++ks) {
      f16x8 af[4], bf[4];
#pragma unroll
      for (int mt = 0; mt < 4; ++mt) {
        int m = wrow + mt * 16 + jlo;
        af[mt] = *(const f16x8*)(As + m * 64 + (((ks * 4 + g) ^ (m & 7)) * 8));
      }
#pragma unroll
      for (int nt = 0; nt < 4; ++nt) {
        int n = wcol + nt * 16 + jlo;
        bf[nt] = *(const f16x8*)(Bs + n * 64 + (((ks * 4 + g) ^ (n & 7)) * 8));
      }
#pragma unroll
      for (int mt = 0; mt < 4; ++mt)
#pragma unroll
        for (int nt = 0; nt < 4; ++nt)
          acc[mt][nt] = MFMA16(af[mt], bf[nt], acc[mt][nt]);
    }
    __syncthreads();
  }
#undef LOADB

#pragma unroll
  for (int nt = 0; nt < 4; ++nt) {
    const int colg = bn * 128 + wcol + nt * 16 + jlo;  // 0..511
    const float bias = bo[colg];
#pragma unroll
    for (int mt = 0; mt < 4; ++mt) {
#pragma unroll
      for (int r = 0; r < 4; ++r)
        out[rowoff[wrow + mt * 16 + g * 4 + r] + colg] = acc[mt][nt][r] + bias;
    }
  }
}

extern "C" void kernel_launch(void* const* d_in, const int* in_sizes, int n_in,
                              void* d_out, int out_size, void* d_ws, size_t ws_size,
                              hipStream_t stream) {
  const float* x  = (const float*)d_in[0];
  const float* wq = (const float*)d_in[1];
  const float* bq = (const float*)d_in[2];
  const float* wo = (const float*)d_in[3];
  const float* bo = (const float*)d_in[4];
  float* out = (float*)d_out;

  f16* qk = (f16*)d_out;                           // q|k overlay (128 MiB)
  f16* xg = (f16*)d_ws;                            // gathered f16 x (64 MiB)
  f16* vt = (f16*)((char*)d_ws + (64u << 20));     // V transposed (64 MiB)
  f16* ao = xg;                                    // reuse: xg dead after k_qkv

  k_pre<<<dim3(4096), 256, 0, stream>>>(x, xg);
  k_qkv<<<dim3(6144), 256, 0, stream>>>(xg, wq, bq, qk, vt);
  k_attn<<<dim3(1024), 256, 0, stream>>>(qk, vt, ao);
  k_out<<<dim3(2048), 256, 0, stream>>>(ao, wo, bo, out);
}